// Round 1
// baseline (296.951 us; speedup 1.0000x reference)
//
#include <hip/hip_runtime.h>
#include <hip/hip_bf16.h>
#include <cmath>

#define B_   2
#define S_   2048
#define D_   768
#define H_   12
#define HD_  64
#define WIN_ 64

typedef __bf16 bf16x8 __attribute__((ext_vector_type(8)));
typedef float  f32x4  __attribute__((ext_vector_type(4)));

// ---------------------------------------------------------------------------
// GEMM: C[M,N] = A[M,K] * Bw[N,K]^T.  fp32 in/out, bf16 MFMA internally.
// Block = 256 threads (4 waves), 128x128 tile, BK=32, wave = 64x64 (4x4 MFMA).
// ---------------------------------------------------------------------------
#define BM 128
#define BN 128
#define BK 32

__global__ __launch_bounds__(256) void gemm_bt(const float* __restrict__ A,
                                               const float* __restrict__ Bw,
                                               float* __restrict__ C,
                                               int M, int N, int K) {
    __shared__ __attribute__((aligned(16))) __bf16 As[BM][BK];
    __shared__ __attribute__((aligned(16))) __bf16 Bs[BN][BK];

    const int tid  = threadIdx.x;
    const int m0   = blockIdx.y * BM;
    const int n0   = blockIdx.x * BN;
    const int w    = tid >> 6;
    const int lane = tid & 63;
    const int wm   = (w >> 1) * 64;   // wave sub-tile origin (rows)
    const int wn   = (w & 1) * 64;    // wave sub-tile origin (cols)
    const int fr   = lane & 15;       // m for A-frag, n for B-frag
    const int fq   = lane >> 4;       // k-octet

    // staging: thread t loads row t/2, 16 consecutive floats at col (t&1)*16
    const int srow = tid >> 1;
    const int scol = (tid & 1) * 16;

    f32x4 acc[4][4] = {};

    for (int k0 = 0; k0 < K; k0 += BK) {
        const float* ag = A  + (size_t)(m0 + srow) * K + k0 + scol;
        const float* bg = Bw + (size_t)(n0 + srow) * K + k0 + scol;
        float4 a0 = ((const float4*)ag)[0];
        float4 a1 = ((const float4*)ag)[1];
        float4 a2 = ((const float4*)ag)[2];
        float4 a3 = ((const float4*)ag)[3];
        float4 b0 = ((const float4*)bg)[0];
        float4 b1 = ((const float4*)bg)[1];
        float4 b2 = ((const float4*)bg)[2];
        float4 b3 = ((const float4*)bg)[3];

        bf16x8 pa0 = { (__bf16)a0.x,(__bf16)a0.y,(__bf16)a0.z,(__bf16)a0.w,
                       (__bf16)a1.x,(__bf16)a1.y,(__bf16)a1.z,(__bf16)a1.w };
        bf16x8 pa1 = { (__bf16)a2.x,(__bf16)a2.y,(__bf16)a2.z,(__bf16)a2.w,
                       (__bf16)a3.x,(__bf16)a3.y,(__bf16)a3.z,(__bf16)a3.w };
        bf16x8 pb0 = { (__bf16)b0.x,(__bf16)b0.y,(__bf16)b0.z,(__bf16)b0.w,
                       (__bf16)b1.x,(__bf16)b1.y,(__bf16)b1.z,(__bf16)b1.w };
        bf16x8 pb1 = { (__bf16)b2.x,(__bf16)b2.y,(__bf16)b2.z,(__bf16)b2.w,
                       (__bf16)b3.x,(__bf16)b3.y,(__bf16)b3.z,(__bf16)b3.w };

        *(bf16x8*)(&As[srow][scol])     = pa0;
        *(bf16x8*)(&As[srow][scol + 8]) = pa1;
        *(bf16x8*)(&Bs[srow][scol])     = pb0;
        *(bf16x8*)(&Bs[srow][scol + 8]) = pb1;

        __syncthreads();

        bf16x8 af[4], bfv[4];
        #pragma unroll
        for (int t = 0; t < 4; ++t) {
            af[t]  = *(const bf16x8*)(&As[wm + t*16 + fr][fq*8]);
            bfv[t] = *(const bf16x8*)(&Bs[wn + t*16 + fr][fq*8]);
        }
        #pragma unroll
        for (int ti = 0; ti < 4; ++ti)
            #pragma unroll
            for (int tj = 0; tj < 4; ++tj)
                acc[ti][tj] = __builtin_amdgcn_mfma_f32_16x16x32_bf16(
                    af[ti], bfv[tj], acc[ti][tj], 0, 0, 0);

        __syncthreads();
    }

    // C/D layout (verified m89): col = lane&15, row = (lane>>4)*4 + reg
    #pragma unroll
    for (int ti = 0; ti < 4; ++ti)
        #pragma unroll
        for (int tj = 0; tj < 4; ++tj) {
            const int col = n0 + wn + tj*16 + fr;
            #pragma unroll
            for (int r = 0; r < 4; ++r) {
                const int row = m0 + wm + ti*16 + fq*4 + r;
                C[(size_t)row * N + col] = acc[ti][tj][r];
            }
        }
}

// ---------------------------------------------------------------------------
// RoPE in place on qkv [B*S, 3*D]; q at +0, k at +D_.  One thread per
// (token, head, dim-pair).
// ---------------------------------------------------------------------------
__global__ __launch_bounds__(256) void rope_kernel(float* __restrict__ qkv,
                                                   const int* __restrict__ pos_ids) {
    const int total = B_ * S_ * H_ * 32;
    int idx = blockIdx.x * 256 + threadIdx.x;
    if (idx >= total) return;
    const int d = idx & 31;
    const int h = (idx >> 5) % H_;
    const int m = idx / (32 * H_);

    const float pos = (float)pos_ids[m];
    const float inv_freq = __powf(10000.0f, -(float)d * (1.0f / 32.0f));
    const float fr = pos * inv_freq;
    float s, c;
    sincosf(fr, &s, &c);

    float* qp = qkv + (size_t)m * (3 * D_) + h * HD_ + d;
    const float q1 = qp[0], q2 = qp[32];
    qp[0]  = q1 * c - q2 * s;
    qp[32] = q2 * c + q1 * s;

    float* kp = qp + D_;
    const float k1 = kp[0], k2 = kp[32];
    kp[0]  = k1 * c - k2 * s;
    kp[32] = k2 * c + k1 * s;
}

// ---------------------------------------------------------------------------
// Banded attention.  Block = (16 queries, head, batch), 256 threads = 4 waves,
// 4 queries per wave.  K staged to LDS (pad +1), softmax, restage V into the
// same buffer, weighted sum with lane = dim.
// ---------------------------------------------------------------------------
#define TQ    16
#define NJMAX (TQ + 2 * WIN_)   // 144

__global__ __launch_bounds__(256) void attn_kernel(const float* __restrict__ qkv,
                                                   float* __restrict__ out) {
    __shared__ float kv[NJMAX][HD_ + 1];
    __shared__ float qs[TQ][HD_];
    __shared__ float ps[TQ][NJMAX];

    const int i0  = blockIdx.x * TQ;
    const int h   = blockIdx.y;
    const int b   = blockIdx.z;
    const int tid = threadIdx.x;
    const int w = tid >> 6, lane = tid & 63;

    const int jlo = max(0, i0 - WIN_);
    const int jhi = min(S_ - 1, i0 + TQ - 1 + WIN_);
    const int nj  = jhi - jlo + 1;

    const float* base = qkv + (size_t)b * S_ * (3 * D_);

    // stage K band
    for (int idx = tid; idx < nj * HD_; idx += 256) {
        const int r = idx >> 6, d = idx & 63;
        kv[r][d] = base[(size_t)(jlo + r) * (3 * D_) + D_ + h * HD_ + d];
    }
    // stage Q tile
    for (int idx = tid; idx < TQ * HD_; idx += 256) {
        const int r = idx >> 6, d = idx & 63;
        qs[r][d] = base[(size_t)(i0 + r) * (3 * D_) + h * HD_ + d];
    }
    __syncthreads();

    float rsumv[TQ / 4];

    // phase 1: scores + softmax weights into ps
    for (int rq = 0; rq < TQ / 4; ++rq) {
        const int qi = w * (TQ / 4) + rq;
        const int i  = i0 + qi;
        const int wlo  = max(0, i - WIN_) - jlo;
        const int whi  = min(S_ - 1, i + WIN_) - jlo;
        const int nwin = whi - wlo + 1;          // <= 129

        float sv[3];
        int cnt = 0;
        float smax = -1e30f;
        for (int jo = lane; jo < nwin; jo += 64) {
            const float* kr = kv[wlo + jo];
            float a = 0.f;
            #pragma unroll
            for (int d = 0; d < HD_; ++d) a += qs[qi][d] * kr[d];
            a *= 0.125f;                          // HD^-0.5
            sv[cnt++] = a;
            smax = fmaxf(smax, a);
        }
        #pragma unroll
        for (int off = 32; off > 0; off >>= 1)
            smax = fmaxf(smax, __shfl_xor(smax, off, 64));

        float ssum = 0.f;
        cnt = 0;
        for (int jo = lane; jo < nwin; jo += 64) {
            const float p = __expf(sv[cnt++] - smax);
            ssum += p;
            ps[qi][wlo + jo] = p;
        }
        #pragma unroll
        for (int off = 32; off > 0; off >>= 1)
            ssum += __shfl_xor(ssum, off, 64);
        rsumv[rq] = 1.0f / ssum;
    }
    __syncthreads();

    // restage V over the K buffer
    for (int idx = tid; idx < nj * HD_; idx += 256) {
        const int r = idx >> 6, d = idx & 63;
        kv[r][d] = base[(size_t)(jlo + r) * (3 * D_) + 2 * D_ + h * HD_ + d];
    }
    __syncthreads();

    // phase 2: O = P * V, lane = head dim
    for (int rq = 0; rq < TQ / 4; ++rq) {
        const int qi = w * (TQ / 4) + rq;
        const int i  = i0 + qi;
        const int wlo  = max(0, i - WIN_) - jlo;
        const int whi  = min(S_ - 1, i + WIN_) - jlo;
        const int nwin = whi - wlo + 1;

        float oacc = 0.f;
        for (int jo = 0; jo < nwin; ++jo)
            oacc += ps[qi][wlo + jo] * kv[wlo + jo][lane];

        out[((size_t)(b * S_ + i)) * D_ + h * HD_ + lane] = oacc * rsumv[rq];
    }
}

// ---------------------------------------------------------------------------
extern "C" void kernel_launch(void* const* d_in, const int* in_sizes, int n_in,
                              void* d_out, int out_size, void* d_ws, size_t ws_size,
                              hipStream_t stream) {
    const float* hs   = (const float*)d_in[0];   // [B,S,D]
    const float* wqkv = (const float*)d_in[1];   // [3D,D]
    const float* wo   = (const float*)d_in[2];   // [D,D]
    // d_in[3] = sliding_window_mask (band structure known analytically; unused)
    const int*   pos  = (const int*)d_in[4];     // [B,S]
    float* out = (float*)d_out;

    float* qkv  = (float*)d_ws;                        // [4096, 2304] fp32
    float* attn = qkv + (size_t)(B_ * S_) * (3 * D_);  // [4096, 768] fp32

    // 1) qkv = hs @ Wqkv^T
    gemm_bt<<<dim3((3 * D_) / BN, (B_ * S_) / BM), 256, 0, stream>>>(
        hs, wqkv, qkv, B_ * S_, 3 * D_, D_);

    // 2) RoPE on q and k (in place)
    rope_kernel<<<(B_ * S_ * H_ * 32 + 255) / 256, 256, 0, stream>>>(qkv, pos);

    // 3) banded attention
    attn_kernel<<<dim3(S_ / TQ, H_, B_), 256, 0, stream>>>(qkv, attn);

    // 4) out = attn @ Wo^T
    gemm_bt<<<dim3(D_ / BN, (B_ * S_) / BM), 256, 0, stream>>>(
        attn, wo, out, B_ * S_, D_, D_);
}

// Round 2
// 161.873 us; speedup vs baseline: 1.8345x; 1.8345x over previous
//
#include <hip/hip_runtime.h>
#include <hip/hip_bf16.h>
#include <cmath>

#define B_   2
#define S_   2048
#define D_   768
#define H_   12
#define HD_  64
#define WIN_ 64

typedef __bf16 bf16x8 __attribute__((ext_vector_type(8)));
typedef __bf16 bf16x4 __attribute__((ext_vector_type(4)));
typedef float  f32x4  __attribute__((ext_vector_type(4)));
typedef unsigned int u32;

// async global->LDS, 16B per lane.  LDS dest must be wave-uniform base + lane*16.
__device__ __forceinline__ void async_ld16(const void* g, void* l) {
    __builtin_amdgcn_global_load_lds(
        (__attribute__((address_space(1))) void*)(size_t)g,
        (__attribute__((address_space(3))) void*)(u32)(size_t)l,
        16, 0, 0);
}

// ---------------------------------------------------------------------------
// fp32 -> bf16 convert for hs / Wqkv / Wo (one pass)
// ---------------------------------------------------------------------------
#define NHS (B_ * S_ * D_)        // 3145728
#define NWQ (3 * D_ * D_)         // 1769472
#define NWO (D_ * D_)             //  589824

__global__ __launch_bounds__(256) void to_bf16_3(const float* __restrict__ a,
                                                 const float* __restrict__ b,
                                                 const float* __restrict__ c,
                                                 __bf16* __restrict__ oa,
                                                 __bf16* __restrict__ ob,
                                                 __bf16* __restrict__ oc) {
    const int NA = NHS / 4, NB = NWQ / 4;
    int v = blockIdx.x * 256 + threadIdx.x;
    const float* src; __bf16* dst; int idx;
    if (v < NA)           { src = a; dst = oa; idx = v; }
    else if (v < NA + NB) { src = b; dst = ob; idx = v - NA; }
    else                  { src = c; dst = oc; idx = v - NA - NB; }
    float4 x = ((const float4*)src)[idx];
    bf16x4 y = { (__bf16)x.x, (__bf16)x.y, (__bf16)x.z, (__bf16)x.w };
    *(bf16x4*)(dst + (size_t)idx * 4) = y;
}

// ---------------------------------------------------------------------------
// GEMM: C[M,N] = A[M,K] * Bw[N,K]^T, bf16 in, MFMA, m97-style async staging.
// MODE 0: fp32 C out.  MODE 1: split epilogue -> qkv bf16 (n<1536) / vt bf16.
// ---------------------------------------------------------------------------
#define BM 128
#define BN 128
#define BK 32

template <int MODE>
__global__ __launch_bounds__(256) void gemm_as(const __bf16* __restrict__ A,
                                               const __bf16* __restrict__ Bw,
                                               float* __restrict__ C,
                                               __bf16* __restrict__ qkv,
                                               __bf16* __restrict__ vt,
                                               int M, int N, int K) {
    __shared__ __attribute__((aligned(16))) __bf16 As[BM * BK];
    __shared__ __attribute__((aligned(16))) __bf16 Bs[BN * BK];

    const int tid  = threadIdx.x;
    const int m0   = blockIdx.y * BM;
    const int n0   = blockIdx.x * BN;
    const int w    = tid >> 6;
    const int lane = tid & 63;
    const int wm   = (w >> 1) * 64;
    const int wn   = (w & 1) * 64;
    const int fr   = lane & 15;
    const int fq   = lane >> 4;

    f32x4 acc[4][4] = {};

    for (int k0 = 0; k0 < K; k0 += BK) {
        #pragma unroll
        for (int i = 0; i < 2; ++i) {
            int c = i * 256 + tid;
            int row = c >> 2, cc = c & 3;
            async_ld16(A  + (size_t)(m0 + row) * K + k0 + cc * 8, As + c * 8);
            async_ld16(Bw + (size_t)(n0 + row) * K + k0 + cc * 8, Bs + c * 8);
        }
        __syncthreads();

        bf16x8 af[4], bfv[4];
        #pragma unroll
        for (int t = 0; t < 4; ++t) {
            af[t]  = *(const bf16x8*)(As + (wm + t * 16 + fr) * BK + fq * 8);
            bfv[t] = *(const bf16x8*)(Bs + (wn + t * 16 + fr) * BK + fq * 8);
        }
        #pragma unroll
        for (int ti = 0; ti < 4; ++ti)
            #pragma unroll
            for (int tj = 0; tj < 4; ++tj)
                acc[ti][tj] = __builtin_amdgcn_mfma_f32_16x16x32_bf16(
                    af[ti], bfv[tj], acc[ti][tj], 0, 0, 0);

        __syncthreads();
    }

    // C/D layout: col = lane&15, row = (lane>>4)*4 + reg
    if (MODE == 0) {
        #pragma unroll
        for (int ti = 0; ti < 4; ++ti)
            #pragma unroll
            for (int tj = 0; tj < 4; ++tj) {
                const int col = n0 + wn + tj * 16 + fr;
                #pragma unroll
                for (int r = 0; r < 4; ++r) {
                    const int row = m0 + wm + ti * 16 + fq * 4 + r;
                    C[(size_t)row * N + col] = acc[ti][tj][r];
                }
            }
    } else {
        if (n0 < 2 * D_) {   // q,k -> qkv[token][1536]
            #pragma unroll
            for (int ti = 0; ti < 4; ++ti)
                #pragma unroll
                for (int tj = 0; tj < 4; ++tj) {
                    const int col = n0 + wn + tj * 16 + fr;
                    #pragma unroll
                    for (int r = 0; r < 4; ++r) {
                        const int row = m0 + wm + ti * 16 + fq * 4 + r;
                        qkv[(size_t)row * (2 * D_) + col] = (__bf16)acc[ti][tj][r];
                    }
                }
        } else {             // v -> vt[b][h][d][token]
            #pragma unroll
            for (int ti = 0; ti < 4; ++ti)
                #pragma unroll
                for (int tj = 0; tj < 4; ++tj) {
                    const int col = n0 + wn + tj * 16 + fr - 2 * D_;
                    const int h = col >> 6, d = col & 63;
                    const int row0 = m0 + wm + ti * 16 + fq * 4;
                    const int bb = row0 >> 11, t0 = row0 & (S_ - 1);
                    bf16x4 pk = { (__bf16)acc[ti][tj][0], (__bf16)acc[ti][tj][1],
                                  (__bf16)acc[ti][tj][2], (__bf16)acc[ti][tj][3] };
                    *(bf16x4*)(vt + ((size_t)((bb * H_ + h) * HD_ + d)) * S_ + t0) = pk;
                }
        }
    }
}

// ---------------------------------------------------------------------------
// RoPE in place on bf16 qkv [B*S, 1536] (q at 0, k at 768)
// ---------------------------------------------------------------------------
__global__ __launch_bounds__(256) void rope_bf(__bf16* __restrict__ qkv,
                                               const int* __restrict__ pos_ids) {
    int idx = blockIdx.x * 256 + threadIdx.x;   // grid sized exactly
    const int d = idx & 31;
    const int h = (idx >> 5) % H_;
    const int m = idx / (32 * H_);

    const float pos = (float)pos_ids[m];
    const float inv_freq = __powf(10000.0f, -(float)d * (1.0f / 32.0f));
    float s, c;
    sincosf(pos * inv_freq, &s, &c);

    __bf16* qp = qkv + (size_t)m * (2 * D_) + h * HD_ + d;
    const float q1 = (float)qp[0], q2 = (float)qp[32];
    qp[0]  = (__bf16)(q1 * c - q2 * s);
    qp[32] = (__bf16)(q2 * c + q1 * s);

    __bf16* kp = qp + D_;
    const float k1 = (float)kp[0], k2 = (float)kp[32];
    kp[0]  = (__bf16)(k1 * c - k2 * s);
    kp[32] = (__bf16)(k2 * c + k1 * s);
}

// ---------------------------------------------------------------------------
// MFMA banded attention.  Block = 64 queries x (head, batch), 4 waves.
// LDS panels of 32 along k so all frag reads are contiguous b128.
//   Qs  [2][64][32]   (4096 el, 8 KB)
//   Ks  [2][192][32]  (12288 el, 24 KB)  -- overlaid by P after scores
//   Vts [6][64][32]   (12288 el, 24 KB)  (V^T: rows = head dim, cols = keys)
// ---------------------------------------------------------------------------
__global__ __launch_bounds__(256) void attn_mfma(const __bf16* __restrict__ qkv,
                                                 const __bf16* __restrict__ vt,
                                                 __bf16* __restrict__ outb) {
    __shared__ __attribute__((aligned(16))) __bf16 smem[28672];  // 56 KB
    __bf16* Qs  = smem;
    __bf16* Ks  = smem + 4096;
    __bf16* Vts = smem + 16384;

    const int i0  = blockIdx.x * 64;
    const int h   = blockIdx.y;
    const int b   = blockIdx.z;
    const int tid = threadIdx.x;
    const int w = tid >> 6, lane = tid & 63;
    const int fr = lane & 15, fq = lane >> 4;
    const int wq0 = w * 16;

    // ---- stage Q (512 chunks), K (1536), Vt (1536) via async copy ----
    const size_t qrow0 = ((size_t)b * S_ + i0) * (2 * D_) + h * HD_;
    #pragma unroll
    for (int i = 0; i < 2; ++i) {
        int c = i * 256 + tid;
        int cc = c & 3, row = (c >> 2) & 63, ks = c >> 8;
        async_ld16(qkv + qrow0 + (size_t)row * (2 * D_) + ks * 32 + cc * 8,
                   Qs + c * 8);
    }
    #pragma unroll
    for (int i = 0; i < 6; ++i) {
        int c = i * 256 + tid;
        int ks = (i >= 3);
        int rem = c - ks * 768;
        int cc = rem & 3, row = rem >> 2;
        int j = i0 - 64 + row; j = min(max(j, 0), S_ - 1);   // clamped addr; masked later
        async_ld16(qkv + ((size_t)b * S_ + j) * (2 * D_) + D_ + h * HD_ + ks * 32 + cc * 8,
                   Ks + c * 8);
    }
    const size_t vbase = (size_t)((b * H_ + h) * HD_) * S_;
    #pragma unroll
    for (int i = 0; i < 6; ++i) {
        int c = i * 256 + tid;
        int ks = c >> 8, rem = c & 255, d = rem >> 2, cc = rem & 3;
        int key = i0 - 64 + ks * 32 + cc * 8;
        key = min(max(key, 0), S_ - 8);                      // clamped addr; masked later
        async_ld16(vt + vbase + (size_t)d * S_ + key, Vts + c * 8);
    }
    __syncthreads();

    // ---- QK^T: S[16 q][192 keys] per wave ----
    bf16x8 aq[2];
    aq[0] = *(const bf16x8*)(Qs + (0 * 64 + wq0 + fr) * 32 + fq * 8);
    aq[1] = *(const bf16x8*)(Qs + (1 * 64 + wq0 + fr) * 32 + fq * 8);

    f32x4 sc[12] = {};
    #pragma unroll
    for (int nt = 0; nt < 12; ++nt) {
        #pragma unroll
        for (int ks = 0; ks < 2; ++ks) {
            bf16x8 bk = *(const bf16x8*)(Ks + (ks * 192 + nt * 16 + fr) * 32 + fq * 8);
            sc[nt] = __builtin_amdgcn_mfma_f32_16x16x32_bf16(aq[ks], bk, sc[nt], 0, 0, 0);
        }
    }

    // ---- mask + softmax (C layout: col j <- fr, rows q <- fq*4+r) ----
    float mx[4] = { -1e30f, -1e30f, -1e30f, -1e30f };
    #pragma unroll
    for (int nt = 0; nt < 12; ++nt) {
        const int jr = nt * 16 + fr;          // key - (i0-64)
        const int j  = i0 - 64 + jr;
        const bool jv = (j >= 0) && (j < S_);
        #pragma unroll
        for (int r = 0; r < 4; ++r) {
            const int ir = wq0 + fq * 4 + r + 64;   // query - (i0-64)
            const int dd = ir - jr;
            const bool v = jv && (dd <= WIN_) && (dd >= -WIN_);
            sc[nt][r] = v ? sc[nt][r] * 0.125f : -1e30f;
            mx[r] = fmaxf(mx[r], sc[nt][r]);
        }
    }
    #pragma unroll
    for (int r = 0; r < 4; ++r)
        #pragma unroll
        for (int off = 1; off < 16; off <<= 1)
            mx[r] = fmaxf(mx[r], __shfl_xor(mx[r], off, 64));

    float sm[4] = { 0.f, 0.f, 0.f, 0.f };
    #pragma unroll
    for (int nt = 0; nt < 12; ++nt)
        #pragma unroll
        for (int r = 0; r < 4; ++r) {
            float e = __expf(sc[nt][r] - mx[r]);
            sc[nt][r] = e;
            sm[r] += e;
        }
    #pragma unroll
    for (int r = 0; r < 4; ++r) {
        #pragma unroll
        for (int off = 1; off < 16; off <<= 1)
            sm[r] += __shfl_xor(sm[r], off, 64);
        sm[r] = 1.0f / sm[r];
    }

    __syncthreads();   // all waves done reading Ks before P overwrites it

    // ---- write normalized P (bf16) into per-wave [6][16][32] panels over Ks ----
    __bf16* Pw = Ks + w * 3072;
    #pragma unroll
    for (int nt = 0; nt < 12; ++nt) {
        const int ks = nt >> 1, kk = (nt & 1) * 16 + fr;
        #pragma unroll
        for (int r = 0; r < 4; ++r)
            Pw[(ks * 16 + fq * 4 + r) * 32 + kk] = (__bf16)(sc[nt][r] * sm[r]);
    }

    // ---- O = P * V  (A = P [q][k] panels, B = V^T panels) ----
    f32x4 oacc[4] = {};
    #pragma unroll
    for (int ks = 0; ks < 6; ++ks) {
        bf16x8 ap = *(const bf16x8*)(Pw + (ks * 16 + fr) * 32 + fq * 8);
        #pragma unroll
        for (int nt2 = 0; nt2 < 4; ++nt2) {
            bf16x8 bv = *(const bf16x8*)(Vts + (ks * 64 + nt2 * 16 + fr) * 32 + fq * 8);
            oacc[nt2] = __builtin_amdgcn_mfma_f32_16x16x32_bf16(ap, bv, oacc[nt2], 0, 0, 0);
        }
    }

    const size_t obase = ((size_t)b * S_ + i0 + wq0) * D_ + h * HD_;
    #pragma unroll
    for (int nt2 = 0; nt2 < 4; ++nt2)
        #pragma unroll
        for (int r = 0; r < 4; ++r)
            outb[obase + (size_t)(fq * 4 + r) * D_ + nt2 * 16 + fr] = (__bf16)oacc[nt2][r];
}

// ---------------------------------------------------------------------------
extern "C" void kernel_launch(void* const* d_in, const int* in_sizes, int n_in,
                              void* d_out, int out_size, void* d_ws, size_t ws_size,
                              hipStream_t stream) {
    const float* hs   = (const float*)d_in[0];
    const float* wqkv = (const float*)d_in[1];
    const float* wo   = (const float*)d_in[2];
    const int*   pos  = (const int*)d_in[4];
    float* out = (float*)d_out;

    __bf16* base    = (__bf16*)d_ws;
    __bf16* hs_bf   = base;                          // 3,145,728
    __bf16* wqkv_bf = hs_bf + NHS;                   // 1,769,472
    __bf16* wo_bf   = wqkv_bf + NWQ;                 //   589,824
    __bf16* qkv     = wo_bf + NWO;                   // 4096*1536
    __bf16* vt      = qkv + (size_t)(B_ * S_) * (2 * D_);   // 2*12*64*2048
    __bf16* attn_bf = vt + (size_t)B_ * H_ * HD_ * S_;      // 4096*768

    // 1) fp32 -> bf16
    to_bf16_3<<<(NHS + NWQ + NWO) / 1024, 256, 0, stream>>>(
        hs, wqkv, wo, hs_bf, wqkv_bf, wo_bf);

    // 2) qkv = hs @ Wqkv^T  (q,k -> qkv bf16; v -> vt transposed)
    gemm_as<1><<<dim3((3 * D_) / BN, (B_ * S_) / BM), 256, 0, stream>>>(
        hs_bf, wqkv_bf, nullptr, qkv, vt, B_ * S_, 3 * D_, D_);

    // 3) RoPE on q,k
    rope_bf<<<(B_ * S_ * H_ * 32) / 256, 256, 0, stream>>>(qkv, pos);

    // 4) banded MFMA attention
    attn_mfma<<<dim3(S_ / 64, H_, B_), 256, 0, stream>>>(qkv, vt, attn_bf);

    // 5) out = attn @ Wo^T (fp32 out)
    gemm_as<0><<<dim3(D_ / BN, (B_ * S_) / BM), 256, 0, stream>>>(
        attn_bf, wo_bf, out, nullptr, nullptr, B_ * S_, D_, D_);
}